// Round 2
// 73.554 us; speedup vs baseline: 1.0182x; 1.0182x over previous
//
#include <hip/hip_runtime.h>
#include <stdint.h>

#define F_FIELDS 17
#define HH 300
#define WW 400
#define H_F 38
#define W_F 50
#define PTS_PER_FIELD (H_F * W_F)     // 1900
#define RAD 13

// Block = 32x32 pixel region, binned into 4x4 tiles of 8x8.
// 256 threads = 4 waves; each wave owns a 16x16 quadrant = four 8x8 tiles
// processed sequentially with ONE pixel per lane (64 lanes = 8x8).
//
// Why 8x8: candidate count per tile ~= ((T + 2*E[rp])/8)^2; T=16 gives ~15
// candidates serving 256 px (28% of pairs inside bbox), T=8 gives ~8.4
// serving 64 px (~50% inside). Phase-2 VALU work per pixel drops ~2x.
// Candidate broadcast moved off the VALU pipe: wave-uniform ds_read_b128
// (LDS broadcast, conflict-free) replaces 5 v_readlane per candidate.
//
// Round 1 note: this exact kernel hit "MI355X container failed twice" with
// no kernel error / no absmax. Audit (global-access bounds, LDS bounds,
// wave-uniform control flow, no divergent barrier) found nothing the GPU
// could fault on; prior session saw the same transient infra crash once and
// the resubmit passed. Resubmitting unchanged.
#define GX 13
#define GY 10
#define NT 16      // 4x4 tiles per block
#define CAP 48     // per-tile list cap; mean n ~= 8.4, hard bound ~25-30
                   // (cx window is 8+2*12=32 px -> <=5x5 grid cols/rows,
                   //  jitter strays add few); 48 is never reached.
// LDS: 16*48*(16+4) + 64 = 15.4 KB -> 8 blocks/CU (wave-slot limited).

// Neighborhood scan unchanged from the verified kernel: 16x16 grid points,
// one per thread, >=8.9 sigma jitter margin before a reachable point could
// be missed; exact per-point bbox test below is the real filter.

__global__ __launch_bounds__(256) void cifhr_fused_kernel(
    const float* __restrict__ x, const float* __restrict__ cifhr,
    float* __restrict__ out) {
    __shared__ float4 sA[NT][CAP];   // px, py, value(=v/16), c(=-1/(16*sigma2))
    __shared__ float  sB[NT][CAP];   // trunc2 = 4*sigma2 (exact, bit-matches ref cmp)
    __shared__ int    cnt[NT];

    const int tid = threadIdx.x;
    const int f  = blockIdx.z;
    const int X0 = blockIdx.x * 32;
    const int Y0 = blockIdx.y * 32;
    const int xvhi = min(X0 + 31, WW - 1);
    const int yvhi = min(Y0 + 31, HH - 1);
    const int txmax = (xvhi - X0) >> 3;   // 0..3 (clips tiles past image edge)
    const int tymax = (yvhi - Y0) >> 3;

    if (tid < NT) cnt[tid] = 0;
    __syncthreads();

    // ---- Phase 1: 16x16 grid-neighborhood scan, one point per thread ----
    const float* base = x + (size_t)(f * 5) * PTS_PER_FIELD;
    const int jlo = (X0 >> 3) - 6;            // X0 % 32 == 0 -> exact X0/8
    const int ilo = (Y0 >> 3) - 6;
    const int i = ilo + (tid >> 4);
    const int j = jlo + (tid & 15);
    const bool ok = (i >= 0) & (i < H_F) & (j >= 0) & (j < W_F);
    const int p = ok ? (i * W_F + j) : 0;      // clamped when unused

    float v = 0.f, xr = 0.f, yr = 0.f, sc = 0.f;
    if (ok) {                                  // 4 independent loads, one batch
        v  = base[p];
        xr = base[PTS_PER_FIELD + p];
        yr = base[2 * PTS_PER_FIELD + p];
        sc = base[4 * PTS_PER_FIELD + p];
    }
    if (ok && (v >= 0.1f) && (sc * 8.0f >= 0.0f)) {   // V_TH, MIN_SCALE
        float px = xr * 8.0f;                  // STRIDE = 8 (exact pow2)
        float py = yr * 8.0f;
        int cx = (int)rintf(px);               // jnp.round = half-even
        int cy = (int)rintf(py);
        float sigma  = fmaxf(1.0f, 4.0f * sc); // 0.5*scale*8
        float sigma2 = sigma * sigma;
        // d2 <= 4*sigma^2 needs |xx-cx| <= floor(2*sigma+0.5); cap at 13
        int rp = min(RAD, (int)(2.0f * sigma + 0.5f));
        int xlo = cx - rp, xhi = cx + rp;
        int ylo = cy - rp, yhi = cy + rp;
        if (!(xhi < X0 || xlo > xvhi || yhi < Y0 || ylo > yvhi)) {
            int tx0 = max(0, (xlo - X0) >> 3), tx1 = min(txmax, (xhi - X0) >> 3);
            int ty0 = max(0, (ylo - Y0) >> 3), ty1 = min(tymax, (yhi - Y0) >> 3);
            float4 rec = make_float4(px, py, v * 0.0625f,
                                     -1.0f / (16.0f * sigma2));
            float tr = 4.0f * sigma2;
            for (int ty = ty0; ty <= ty1; ++ty)
                for (int tx = tx0; tx <= tx1; ++tx) {
                    int t = ty * 4 + tx;
                    int slot = atomicAdd(&cnt[t], 1);   // LDS atomic
                    if (slot < CAP) { sA[t][slot] = rec; sB[t][slot] = tr; }
                }
        }
    }
    __syncthreads();

    // ---- Phase 2: wave -> 16x16 quadrant = four 8x8 tiles, 1 px/lane ----
    const int s  = tid >> 6, ln = tid & 63;
    const int sx = s & 1, sy = s >> 1;
    const int lx = ln & 7, ly = ln >> 3;

    #pragma unroll
    for (int q = 0; q < 4; ++q) {
        const int tX = (sx << 1) | (q & 1);
        const int tY = (sy << 1) | (q >> 1);
        if (tX > txmax || tY > tymax) continue;   // wave-uniform
        const int t = tY * 4 + tX;
        const int n = min(cnt[t], CAP);           // wave-uniform

        const int xb = X0 + (tX << 3) + lx;       // x always < WW (WW % 8 == 0)
        const int yb = Y0 + (tY << 3) + ly;
        const bool wv = (yb < HH);                // HH % 8 != 0 -> guard rows
        const size_t idx = ((size_t)f * HH + yb) * WW + xb;
        const float c = wv ? cifhr[idx] : 0.0f;   // load early, hide under loop
        const float xf = (float)xb, yf = (float)yb;

        float acc = 0.0f;
        for (int k = 0; k < n; ++k) {
            float4 a  = sA[t][k];                 // uniform addr: ds broadcast
            float  tr = sB[t][k];
            float dx = xf - a.x, dy = yf - a.y;
            float dx2 = dx * dx, dy2 = dy * dy;
            float d2 = dy2 + dx2;                 // ref add order dy2 + dx2
            float u = fmaf(a.w, d2, 1.0f);        // (1 - d2/(16*s2))
            u *= u; u *= u; u *= u;               // ^8
            float g   = (fmaxf(dy2, dx2) < 0.25f) ? 1.0f : u;   // nearest
            float sel = (d2 <= tr) ? a.z : 0.0f;  // exact cutoff cmp vs staged tr
            acc = fmaf(sel, g, acc);
        }
        if (wv) out[idx] = fminf(acc + c, 1.0f);
    }
}

extern "C" void kernel_launch(void* const* d_in, const int* in_sizes, int n_in,
                              void* d_out, int out_size, void* d_ws, size_t ws_size,
                              hipStream_t stream) {
    const float* cifhr = (const float*)d_in[0];
    const float* x     = (const float*)d_in[1];
    float* outp = (float*)d_out;

    dim3 grid(GX, GY, F_FIELDS);   // 13 x 10 x 17 = 2210 blocks
    cifhr_fused_kernel<<<grid, 256, 0, stream>>>(x, cifhr, outp);
}